// Round 1
// baseline (6640.679 us; speedup 1.0000x reference)
//
#include <hip/hip_runtime.h>
#include <cstdint>
#include <cstddef>

// Problem constants (reference: N=4, P1=P2=2048, D=64, eps=0.1, 50 iters)
#define NB 4
#define P1 2048
#define P2 2048
#define DD 64
#define ITER 50
#define EPS 0.1f
#define INV_EPS 10.0f          // 1.0f/0.1f rounds to exactly 10.0f
#define THRESH 0.1f
// log(1/2048 + 1e-8) in fp32
#define LOG_MU -7.6245985f
#define LOG_NU -7.6245985f
#define NCHUNK 16
#define CHUNK (P1 / NCHUNK)    // 128 rows per v-partial chunk

// ---------------------------------------------------------------------------
// Online logsumexp helpers
// ---------------------------------------------------------------------------
__device__ __forceinline__ void lse_merge1(float a, float& m, float& s) {
    float nm = fmaxf(m, a);
    s = s * __expf(m - nm) + __expf(a - nm);
    m = nm;
}

__device__ __forceinline__ void lse_merge4(float a0, float a1, float a2, float a3,
                                           float& m, float& s) {
    float m4 = fmaxf(fmaxf(a0, a1), fmaxf(a2, a3));
    float s4 = __expf(a0 - m4) + __expf(a1 - m4) + __expf(a2 - m4) + __expf(a3 - m4);
    float nm = fmaxf(m, m4);
    s = s * __expf(m - nm) + s4 * __expf(m4 - nm);
    m = nm;
}

__device__ __forceinline__ void lse_merge_pair(float mo, float so, float& m, float& s) {
    float nm = fmaxf(m, mo);
    s = s * __expf(m - nm) + so * __expf(mo - nm);
    m = nm;
}

// ---------------------------------------------------------------------------
// prep0: S = M + M^T, zero err accumulators, init active flags, zero cost out
// ---------------------------------------------------------------------------
__global__ void prep0(const float* __restrict__ M, float* __restrict__ S,
                      float* __restrict__ errAcc, int* __restrict__ active,
                      float* __restrict__ cost) {
    int t = threadIdx.x;
    for (int k = t; k < DD * DD; k += 256) {
        int d = k >> 6, e = k & 63;
        S[k] = M[d * DD + e] + M[e * DD + d];
    }
    if (t < 64) errAcc[t] = 0.0f;
    if (t < 64) active[t] = (t == 0) ? 1 : 0;
    if (t < NB) cost[t] = 0.0f;
}

// ---------------------------------------------------------------------------
// prep1: one wave per row. x-rows: xS = x@S, dx = 0.5*x·(Sx), u=0.
//        y-rows: dy = 0.5*y·(Sy), v=0.  (dx = xMx^T since quad form sees sym part)
// ---------------------------------------------------------------------------
__global__ __launch_bounds__(256) void prep1(const float* __restrict__ x,
                                             const float* __restrict__ y,
                                             const float* __restrict__ S,
                                             float* __restrict__ xS,
                                             float* __restrict__ dx,
                                             float* __restrict__ dy,
                                             float* __restrict__ u,
                                             float* __restrict__ v) {
    __shared__ float Sl[DD * DD];
    int t = threadIdx.x;
    for (int k = t; k < DD * DD; k += 256) Sl[k] = S[k];
    __syncthreads();
    int wave = t >> 6, lane = t & 63;
    int r = blockIdx.x * 4 + wave;          // 0 .. N*(P1+P2)-1
    bool isX = r < NB * P1;
    const float* src = isX ? x : y;
    int rr = isX ? r : r - NB * P1;
    float xv = src[(size_t)rr * DD + lane];
    float acc = 0.0f;
    #pragma unroll
    for (int d = 0; d < DD; ++d) {
        float xd = __shfl(xv, d, 64);
        acc = fmaf(xd, Sl[d * DD + lane], acc);
    }
    float p = acc * xv;
    #pragma unroll
    for (int o = 32; o; o >>= 1) p += __shfl_xor(p, o, 64);
    if (isX) {
        xS[(size_t)rr * DD + lane] = acc;
        if (lane == 0) { dx[rr] = 0.5f * p; u[rr] = 0.0f; }
    } else {
        if (lane == 0) { dy[rr] = 0.5f * p; v[rr] = 0.0f; }
    }
}

// ---------------------------------------------------------------------------
// gemmC: C[n,i,j] = dx[n,i] + dy[n,j] - sum_e xS[n,i,e]*y[n,j,e]
// 64x64 tile per 256-thread block, 4x4 register tile per thread.
// ---------------------------------------------------------------------------
__global__ __launch_bounds__(256) void gemmC(const float* __restrict__ xS,
                                             const float* __restrict__ y,
                                             const float* __restrict__ dx,
                                             const float* __restrict__ dy,
                                             float* __restrict__ C) {
    __shared__ float xs[64][68];   // [e][i_local], padded: 68*4=272 B = 17*16 (float4 aligned)
    __shared__ float ys[64][68];   // [e][j_local]
    int n = blockIdx.z;
    int i0 = blockIdx.y * 64, j0 = blockIdx.x * 64;
    int t = threadIdx.x;

    #pragma unroll
    for (int k = 0; k < 4; ++k) {
        int f = t + 256 * k;       // 0..1023
        int row = f >> 4;          // 0..63
        int c4 = f & 15;           // 0..15
        float4 a = ((const float4*)xS)[((size_t)(n * P1 + i0 + row)) * (DD / 4) + c4];
        xs[4 * c4 + 0][row] = a.x; xs[4 * c4 + 1][row] = a.y;
        xs[4 * c4 + 2][row] = a.z; xs[4 * c4 + 3][row] = a.w;
        float4 b = ((const float4*)y)[((size_t)(n * P2 + j0 + row)) * (DD / 4) + c4];
        ys[4 * c4 + 0][row] = b.x; ys[4 * c4 + 1][row] = b.y;
        ys[4 * c4 + 2][row] = b.z; ys[4 * c4 + 3][row] = b.w;
    }
    __syncthreads();

    int tx = t & 15, ty = t >> 4;
    float acc[4][4] = {};
    #pragma unroll
    for (int e = 0; e < 64; ++e) {
        float4 a = *(const float4*)&xs[e][4 * ty];
        float4 b = *(const float4*)&ys[e][4 * tx];
        acc[0][0] = fmaf(a.x, b.x, acc[0][0]); acc[0][1] = fmaf(a.x, b.y, acc[0][1]);
        acc[0][2] = fmaf(a.x, b.z, acc[0][2]); acc[0][3] = fmaf(a.x, b.w, acc[0][3]);
        acc[1][0] = fmaf(a.y, b.x, acc[1][0]); acc[1][1] = fmaf(a.y, b.y, acc[1][1]);
        acc[1][2] = fmaf(a.y, b.z, acc[1][2]); acc[1][3] = fmaf(a.y, b.w, acc[1][3]);
        acc[2][0] = fmaf(a.z, b.x, acc[2][0]); acc[2][1] = fmaf(a.z, b.y, acc[2][1]);
        acc[2][2] = fmaf(a.z, b.z, acc[2][2]); acc[2][3] = fmaf(a.z, b.w, acc[2][3]);
        acc[3][0] = fmaf(a.w, b.x, acc[3][0]); acc[3][1] = fmaf(a.w, b.y, acc[3][1]);
        acc[3][2] = fmaf(a.w, b.z, acc[3][2]); acc[3][3] = fmaf(a.w, b.w, acc[3][3]);
    }

    int iBase = i0 + ty * 4, jBase = j0 + tx * 4;
    float4 dy4 = *(const float4*)&dy[n * P2 + jBase];
    #pragma unroll
    for (int r = 0; r < 4; ++r) {
        float dxv = dx[n * P1 + iBase + r];
        float4 o;
        o.x = dxv + dy4.x - acc[r][0];
        o.y = dxv + dy4.y - acc[r][1];
        o.z = dxv + dy4.z - acc[r][2];
        o.w = dxv + dy4.w - acc[r][3];
        *(float4*)&C[((size_t)(n * P1 + iBase + r)) * P2 + jBase] = o;
    }
}

// ---------------------------------------------------------------------------
// u_pass: row LSE. One wave per row (4 rows/block); v staged in LDS.
// u_new = eps*(log_mu - LSE_j((u_i - C_ij + v_j)/eps)) + u_i
// Accumulates sum |du| into errAcc[t].
// ---------------------------------------------------------------------------
__global__ __launch_bounds__(256) void u_pass(const float* __restrict__ C,
                                              float* __restrict__ u,
                                              const float* __restrict__ v,
                                              float* __restrict__ errAcc,
                                              const int* __restrict__ active,
                                              int t_iter) {
    if (!active[t_iter]) return;
    __shared__ float vl[P2];
    int t = threadIdx.x;
    int n = blockIdx.x >> 9;                // 512 blocks per batch
    int i0 = (blockIdx.x & 511) * 4;
    const float* vsrc = v + n * P2;
    for (int k = t; k < P2 / 4; k += 256) ((float4*)vl)[k] = ((const float4*)vsrc)[k];
    __syncthreads();

    int wave = t >> 6, lane = t & 63;
    int i = i0 + wave;
    float ui = u[n * P1 + i];
    const float* Crow = C + ((size_t)(n * P1 + i)) * P2;
    float m = -3.4e38f, s = 0.0f;
    #pragma unroll
    for (int k = 0; k < P2 / 256; ++k) {
        int j4 = lane + 64 * k;
        float4 c4 = ((const float4*)Crow)[j4];
        float4 v4 = ((const float4*)vl)[j4];
        float a0 = ((ui - c4.x) + v4.x) * INV_EPS;
        float a1 = ((ui - c4.y) + v4.y) * INV_EPS;
        float a2 = ((ui - c4.z) + v4.z) * INV_EPS;
        float a3 = ((ui - c4.w) + v4.w) * INV_EPS;
        lse_merge4(a0, a1, a2, a3, m, s);
    }
    #pragma unroll
    for (int o = 1; o < 64; o <<= 1) {
        float mo = __shfl_xor(m, o, 64);
        float so = __shfl_xor(s, o, 64);
        lse_merge_pair(mo, so, m, s);
    }
    if (lane == 0) {
        float lse = __logf(s) + m;
        float unew = EPS * (LOG_MU - lse) + ui;
        u[n * P1 + i] = unew;
        atomicAdd(&errAcc[t_iter], fabsf(unew - ui));
    }
}

// ---------------------------------------------------------------------------
// v_part: column LSE partials. One thread per column, CHUNK rows per block.
// ---------------------------------------------------------------------------
__global__ __launch_bounds__(256) void v_part(const float* __restrict__ C,
                                              const float* __restrict__ u,
                                              const float* __restrict__ v,
                                              float* __restrict__ pm,
                                              float* __restrict__ ps,
                                              const int* __restrict__ active,
                                              int t_iter) {
    if (!active[t_iter]) return;
    int n = blockIdx.z, rc = blockIdx.y, jb = blockIdx.x;
    int j = jb * 256 + threadIdx.x;
    float vj = v[n * P2 + j];
    const float* Cb = C + (size_t)n * P1 * P2 + (size_t)(rc * CHUNK) * P2 + j;
    const float* ub = u + n * P1 + rc * CHUNK;
    float m = -3.4e38f, s = 0.0f;
    for (int i = 0; i < CHUNK; i += 4) {
        float a0 = ((ub[i + 0] - Cb[(size_t)(i + 0) * P2]) + vj) * INV_EPS;
        float a1 = ((ub[i + 1] - Cb[(size_t)(i + 1) * P2]) + vj) * INV_EPS;
        float a2 = ((ub[i + 2] - Cb[(size_t)(i + 2) * P2]) + vj) * INV_EPS;
        float a3 = ((ub[i + 3] - Cb[(size_t)(i + 3) * P2]) + vj) * INV_EPS;
        lse_merge4(a0, a1, a2, a3, m, s);
    }
    pm[(n * NCHUNK + rc) * P2 + j] = m;
    ps[(n * NCHUNK + rc) * P2 + j] = s;
}

// ---------------------------------------------------------------------------
// v_comb: combine NCHUNK partials per column, apply v update, update active[t+1].
// active[t+1] uses errAcc[t] (complete: u_pass of iter t already finished).
// ---------------------------------------------------------------------------
__global__ __launch_bounds__(256) void v_comb(const float* __restrict__ pm,
                                              const float* __restrict__ ps,
                                              float* __restrict__ v,
                                              const float* __restrict__ errAcc,
                                              int* __restrict__ active,
                                              int t_iter) {
    if (blockIdx.x == 0 && threadIdx.x == 0) {
        // err = mean over batches = errAcc/NB ; stay active while err >= THRESH
        if (active[t_iter] && (errAcc[t_iter] * 0.25f >= THRESH)) active[t_iter + 1] = 1;
    }
    if (!active[t_iter]) return;
    int gid = blockIdx.x * 256 + threadIdx.x;   // 0..NB*P2-1
    int n = gid >> 11, j = gid & 2047;
    float m = -3.4e38f, s = 0.0f;
    #pragma unroll
    for (int rc = 0; rc < NCHUNK; ++rc) {
        float mi = pm[(n * NCHUNK + rc) * P2 + j];
        float si = ps[(n * NCHUNK + rc) * P2 + j];
        lse_merge_pair(mi, si, m, s);
    }
    float lse = __logf(s) + m;
    float vo = v[n * P2 + j];
    v[n * P2 + j] = EPS * (LOG_NU - lse) + vo;
}

// ---------------------------------------------------------------------------
// final_pass: pi = exp((u_i - C + v_j)/eps), cost_n = sum(pi*C). One block/row.
// ---------------------------------------------------------------------------
__global__ __launch_bounds__(256) void final_pass(const float* __restrict__ C,
                                                  const float* __restrict__ u,
                                                  const float* __restrict__ v,
                                                  float* __restrict__ pi,
                                                  float* __restrict__ cost) {
    int n = blockIdx.x >> 11, i = blockIdx.x & 2047;
    float ui = u[n * P1 + i];
    const float* Crow = C + ((size_t)(n * P1 + i)) * P2;
    float* Prow = pi + ((size_t)(n * P1 + i)) * P2;
    const float* vb = v + n * P2;
    int t = threadIdx.x;
    float acc = 0.0f;
    for (int k = t; k < P2 / 4; k += 256) {
        float4 c4 = ((const float4*)Crow)[k];
        float4 v4 = ((const float4*)vb)[k];
        float4 p4;
        p4.x = __expf(((ui - c4.x) + v4.x) * INV_EPS);
        p4.y = __expf(((ui - c4.y) + v4.y) * INV_EPS);
        p4.z = __expf(((ui - c4.z) + v4.z) * INV_EPS);
        p4.w = __expf(((ui - c4.w) + v4.w) * INV_EPS);
        ((float4*)Prow)[k] = p4;
        acc += p4.x * c4.x + p4.y * c4.y + p4.z * c4.z + p4.w * c4.w;
    }
    int wave = t >> 6, lane = t & 63;
    #pragma unroll
    for (int o = 1; o < 64; o <<= 1) acc += __shfl_xor(acc, o, 64);
    __shared__ float red[4];
    if (lane == 0) red[wave] = acc;
    __syncthreads();
    if (t == 0) atomicAdd(&cost[n], red[0] + red[1] + red[2] + red[3]);
}

// ---------------------------------------------------------------------------
extern "C" void kernel_launch(void* const* d_in, const int* in_sizes, int n_in,
                              void* d_out, int out_size, void* d_ws, size_t ws_size,
                              hipStream_t stream) {
    const float* x = (const float*)d_in[0];   // [N,P1,D]
    const float* y = (const float*)d_in[1];   // [N,P2,D]
    const float* M = (const float*)d_in[2];   // [D,D]
    float* out = (float*)d_out;
    float* cost = out;                                    // [N]
    float* pi = out + NB;                                 // [N,P1,P2]
    float* C = out + NB + (size_t)NB * P1 * P2;           // [N,P1,P2]

    float* ws = (float*)d_ws;
    float* S      = ws;                                   // 4096
    float* xS     = S + DD * DD;                          // N*P1*D
    float* dx     = xS + (size_t)NB * P1 * DD;            // N*P1
    float* dy     = dx + NB * P1;                         // N*P2
    float* u      = dy + NB * P2;                         // N*P1
    float* v      = u + NB * P1;                          // N*P2
    float* pm     = v + NB * P2;                          // N*NCHUNK*P2
    float* ps     = pm + NB * NCHUNK * P2;                // N*NCHUNK*P2
    float* errAcc = ps + NB * NCHUNK * P2;                // 64
    int*   active = (int*)(errAcc + 64);                  // 64 ints

    prep0<<<1, 256, 0, stream>>>(M, S, errAcc, active, cost);
    prep1<<<(NB * (P1 + P2)) / 4, 256, 0, stream>>>(x, y, S, xS, dx, dy, u, v);
    gemmC<<<dim3(P2 / 64, P1 / 64, NB), 256, 0, stream>>>(xS, y, dx, dy, C);
    for (int t = 0; t < ITER; ++t) {
        u_pass<<<NB * P1 / 4, 256, 0, stream>>>(C, u, v, errAcc, active, t);
        v_part<<<dim3(P2 / 256, NCHUNK, NB), 256, 0, stream>>>(C, u, v, pm, ps, active, t);
        v_comb<<<NB * P2 / 256, 256, 0, stream>>>(pm, ps, v, errAcc, active, t);
    }
    final_pass<<<NB * P1, 256, 0, stream>>>(C, u, v, pi, cost);
}

// Round 2
// 2557.718 us; speedup vs baseline: 2.5963x; 2.5963x over previous
//
#include <hip/hip_runtime.h>
#include <cstdint>
#include <cstddef>

// Problem constants (reference: N=4, P1=P2=2048, D=64, eps=0.1, 50 iters)
#define NB 4
#define P1 2048
#define P2 2048
#define DD 64
#define ITER 50
#define EPS 0.1f
#define INV_EPS 10.0f          // 1.0f/0.1f rounds to exactly 10.0f
#define THRESH 0.1f
// log(1/2048 + 1e-8) in fp32
#define LOG_MU -7.6245985f
#define LOG_NU -7.6245985f
#define RCHUNK 8               // rows per fused block
#define NCHUNK (P1 / RCHUNK)   // 256 chunks per batch

__device__ __forceinline__ void lse_merge_pair(float mo, float so, float& m, float& s) {
    float nm = fmaxf(m, mo);
    s = s * __expf(m - nm) + so * __expf(mo - nm);
    m = nm;
}

// ---------------------------------------------------------------------------
// prep0: S = M + M^T, zero err accumulators, init active flags, zero cost out
// ---------------------------------------------------------------------------
__global__ void prep0(const float* __restrict__ M, float* __restrict__ S,
                      float* __restrict__ errAcc, int* __restrict__ active,
                      float* __restrict__ cost) {
    int t = threadIdx.x;
    for (int k = t; k < DD * DD; k += 256) {
        int d = k >> 6, e = k & 63;
        S[k] = M[d * DD + e] + M[e * DD + d];
    }
    if (t < 64) errAcc[t] = 0.0f;
    if (t < 64) active[t] = (t == 0) ? 1 : 0;
    if (t < NB) cost[t] = 0.0f;
}

// ---------------------------------------------------------------------------
// prep1: one wave per row. x-rows: xS = x@S, dx = 0.5*x·(Sx), u=0.
//        y-rows: dy = 0.5*y·(Sy), v=0.
// ---------------------------------------------------------------------------
__global__ __launch_bounds__(256) void prep1(const float* __restrict__ x,
                                             const float* __restrict__ y,
                                             const float* __restrict__ S,
                                             float* __restrict__ xS,
                                             float* __restrict__ dx,
                                             float* __restrict__ dy,
                                             float* __restrict__ u,
                                             float* __restrict__ v) {
    __shared__ float Sl[DD * DD];
    int t = threadIdx.x;
    for (int k = t; k < DD * DD; k += 256) Sl[k] = S[k];
    __syncthreads();
    int wave = t >> 6, lane = t & 63;
    int r = blockIdx.x * 4 + wave;          // 0 .. N*(P1+P2)-1
    bool isX = r < NB * P1;
    const float* src = isX ? x : y;
    int rr = isX ? r : r - NB * P1;
    float xv = src[(size_t)rr * DD + lane];
    float acc = 0.0f;
    #pragma unroll
    for (int d = 0; d < DD; ++d) {
        float xd = __shfl(xv, d, 64);
        acc = fmaf(xd, Sl[d * DD + lane], acc);
    }
    float p = acc * xv;
    #pragma unroll
    for (int o = 32; o; o >>= 1) p += __shfl_xor(p, o, 64);
    if (isX) {
        xS[(size_t)rr * DD + lane] = acc;
        if (lane == 0) { dx[rr] = 0.5f * p; u[rr] = 0.0f; }
    } else {
        if (lane == 0) { dy[rr] = 0.5f * p; v[rr] = 0.0f; }
    }
}

// ---------------------------------------------------------------------------
// gemmC: C[n,i,j] = dx[n,i] + dy[n,j] - sum_e xS[n,i,e]*y[n,j,e]
// 64x64 tile per 256-thread block, 4x4 register tile per thread.
// ---------------------------------------------------------------------------
__global__ __launch_bounds__(256) void gemmC(const float* __restrict__ xS,
                                             const float* __restrict__ y,
                                             const float* __restrict__ dx,
                                             const float* __restrict__ dy,
                                             float* __restrict__ C) {
    __shared__ float xs[64][68];
    __shared__ float ys[64][68];
    int n = blockIdx.z;
    int i0 = blockIdx.y * 64, j0 = blockIdx.x * 64;
    int t = threadIdx.x;

    #pragma unroll
    for (int k = 0; k < 4; ++k) {
        int f = t + 256 * k;       // 0..1023
        int row = f >> 4;          // 0..63
        int c4 = f & 15;           // 0..15
        float4 a = ((const float4*)xS)[((size_t)(n * P1 + i0 + row)) * (DD / 4) + c4];
        xs[4 * c4 + 0][row] = a.x; xs[4 * c4 + 1][row] = a.y;
        xs[4 * c4 + 2][row] = a.z; xs[4 * c4 + 3][row] = a.w;
        float4 b = ((const float4*)y)[((size_t)(n * P2 + j0 + row)) * (DD / 4) + c4];
        ys[4 * c4 + 0][row] = b.x; ys[4 * c4 + 1][row] = b.y;
        ys[4 * c4 + 2][row] = b.z; ys[4 * c4 + 3][row] = b.w;
    }
    __syncthreads();

    int tx = t & 15, ty = t >> 4;
    float acc[4][4] = {};
    #pragma unroll
    for (int e = 0; e < 64; ++e) {
        float4 a = *(const float4*)&xs[e][4 * ty];
        float4 b = *(const float4*)&ys[e][4 * tx];
        acc[0][0] = fmaf(a.x, b.x, acc[0][0]); acc[0][1] = fmaf(a.x, b.y, acc[0][1]);
        acc[0][2] = fmaf(a.x, b.z, acc[0][2]); acc[0][3] = fmaf(a.x, b.w, acc[0][3]);
        acc[1][0] = fmaf(a.y, b.x, acc[1][0]); acc[1][1] = fmaf(a.y, b.y, acc[1][1]);
        acc[1][2] = fmaf(a.y, b.z, acc[1][2]); acc[1][3] = fmaf(a.y, b.w, acc[1][3]);
        acc[2][0] = fmaf(a.z, b.x, acc[2][0]); acc[2][1] = fmaf(a.z, b.y, acc[2][1]);
        acc[2][2] = fmaf(a.z, b.z, acc[2][2]); acc[2][3] = fmaf(a.z, b.w, acc[2][3]);
        acc[3][0] = fmaf(a.w, b.x, acc[3][0]); acc[3][1] = fmaf(a.w, b.y, acc[3][1]);
        acc[3][2] = fmaf(a.w, b.z, acc[3][2]); acc[3][3] = fmaf(a.w, b.w, acc[3][3]);
    }

    int iBase = i0 + ty * 4, jBase = j0 + tx * 4;
    float4 dy4 = *(const float4*)&dy[n * P2 + jBase];
    #pragma unroll
    for (int r = 0; r < 4; ++r) {
        float dxv = dx[n * P1 + iBase + r];
        float4 o;
        o.x = dxv + dy4.x - acc[r][0];
        o.y = dxv + dy4.y - acc[r][1];
        o.z = dxv + dy4.z - acc[r][2];
        o.w = dxv + dy4.w - acc[r][3];
        *(float4*)&C[((size_t)(n * P1 + iBase + r)) * P2 + jBase] = o;
    }
}

// ---------------------------------------------------------------------------
// fused_iter: one block per (batch, 8-row chunk). 512 threads = 8 waves.
// Phase A: wave-per-row LSE (all 8 float4 C-loads prefetched into regs ->
//          deep ILP; max-reduce first, then flat exp-sum), u update.
// Phase B: column-LSE partials (m,s) over this chunk's 8 rows using the
//          fresh u values; C chunk is L1/L2-hot from phase A.
// ---------------------------------------------------------------------------
__global__ __launch_bounds__(512) void fused_iter(const float* __restrict__ C,
                                                  float* __restrict__ u,
                                                  const float* __restrict__ v,
                                                  float* __restrict__ pm,
                                                  float* __restrict__ ps,
                                                  float* __restrict__ errAcc,
                                                  const int* __restrict__ active,
                                                  int t_iter) {
    if (!active[t_iter]) return;
    __shared__ float vl[P2];
    __shared__ float u_s[RCHUNK];
    __shared__ float du_s[RCHUNK];
    int t = threadIdx.x;
    int n = blockIdx.x >> 8;                 // NCHUNK = 256 chunks per batch
    int chunk = blockIdx.x & (NCHUNK - 1);
    int i0 = chunk * RCHUNK;

    // stage v for this batch (2048 floats, 512 threads x float4)
    ((float4*)vl)[t] = ((const float4*)(v + n * P2))[t];
    __syncthreads();

    int wave = t >> 6, lane = t & 63;
    int i = i0 + wave;
    float ui = u[n * P1 + i];
    const float4* Crow4 = (const float4*)(C + ((size_t)(n * P1 + i)) * P2);

    // prefetch the whole row: 8 independent float4 loads in flight
    float4 a[8];
    #pragma unroll
    for (int k = 0; k < 8; ++k) a[k] = Crow4[lane + 64 * k];

    float m = -3.4e38f;
    #pragma unroll
    for (int k = 0; k < 8; ++k) {
        float4 vv = ((const float4*)vl)[lane + 64 * k];
        a[k].x = ((ui - a[k].x) + vv.x) * INV_EPS;
        a[k].y = ((ui - a[k].y) + vv.y) * INV_EPS;
        a[k].z = ((ui - a[k].z) + vv.z) * INV_EPS;
        a[k].w = ((ui - a[k].w) + vv.w) * INV_EPS;
        m = fmaxf(m, fmaxf(fmaxf(a[k].x, a[k].y), fmaxf(a[k].z, a[k].w)));
    }
    #pragma unroll
    for (int o = 1; o < 64; o <<= 1) m = fmaxf(m, __shfl_xor(m, o, 64));
    float s = 0.0f;
    #pragma unroll
    for (int k = 0; k < 8; ++k)
        s += __expf(a[k].x - m) + __expf(a[k].y - m) +
             __expf(a[k].z - m) + __expf(a[k].w - m);
    #pragma unroll
    for (int o = 1; o < 64; o <<= 1) s += __shfl_xor(s, o, 64);

    if (lane == 0) {
        float lse = __logf(s) + m;
        float unew = EPS * (LOG_MU - lse) + ui;
        u[n * P1 + i] = unew;
        u_s[wave] = unew;
        du_s[wave] = fabsf(unew - ui);
    }
    __syncthreads();
    if (t == 0) {
        float e = 0.0f;
        #pragma unroll
        for (int r = 0; r < RCHUNK; ++r) e += du_s[r];
        atomicAdd(&errAcc[t_iter], e);
    }

    // Phase B: column partials over this chunk's 8 rows (4 cols per thread)
    float ur[RCHUNK];
    #pragma unroll
    for (int r = 0; r < RCHUNK; ++r) ur[r] = u_s[r];
    const float* Cb = C + (size_t)n * P1 * P2 + (size_t)i0 * P2;
    size_t pbase = ((size_t)(n * NCHUNK + chunk)) * P2;
    #pragma unroll
    for (int cc = 0; cc < 4; ++cc) {
        int j = t + 512 * cc;
        float vj = vl[j];
        float av[RCHUNK];
        #pragma unroll
        for (int r = 0; r < RCHUNK; ++r)
            av[r] = ((ur[r] - Cb[(size_t)r * P2 + j]) + vj) * INV_EPS;
        float mm = av[0];
        #pragma unroll
        for (int r = 1; r < RCHUNK; ++r) mm = fmaxf(mm, av[r]);
        float ss = 0.0f;
        #pragma unroll
        for (int r = 0; r < RCHUNK; ++r) ss += __expf(av[r] - mm);
        pm[pbase + j] = mm;
        ps[pbase + j] = ss;
    }
}

// ---------------------------------------------------------------------------
// v_comb: combine NCHUNK (m,s) partials per column, apply v update,
// update active[t+1]. 64-thread blocks spread work across more CUs; 4
// interleaved accumulators break the serial merge chain.
// ---------------------------------------------------------------------------
__global__ __launch_bounds__(64) void v_comb(const float* __restrict__ pm,
                                             const float* __restrict__ ps,
                                             float* __restrict__ v,
                                             const float* __restrict__ errAcc,
                                             int* __restrict__ active,
                                             int t_iter) {
    if (blockIdx.x == 0 && threadIdx.x == 0) {
        // err = mean over batches = errAcc/NB ; stay active while err >= THRESH
        if (active[t_iter] && (errAcc[t_iter] * 0.25f >= THRESH)) active[t_iter + 1] = 1;
    }
    if (!active[t_iter]) return;
    int gid = blockIdx.x * 64 + threadIdx.x;   // 0..NB*P2-1
    int n = gid >> 11, j = gid & 2047;
    const float* pmb = pm + (size_t)n * NCHUNK * P2 + j;
    const float* psb = ps + (size_t)n * NCHUNK * P2 + j;
    float m[4] = {-3.4e38f, -3.4e38f, -3.4e38f, -3.4e38f};
    float s[4] = {0.0f, 0.0f, 0.0f, 0.0f};
    for (int rc = 0; rc < NCHUNK; rc += 4) {
        #pragma unroll
        for (int q = 0; q < 4; ++q) {
            float mi = pmb[(size_t)(rc + q) * P2];
            float si = psb[(size_t)(rc + q) * P2];
            lse_merge_pair(mi, si, m[q], s[q]);
        }
    }
    lse_merge_pair(m[1], s[1], m[0], s[0]);
    lse_merge_pair(m[3], s[3], m[2], s[2]);
    lse_merge_pair(m[2], s[2], m[0], s[0]);
    float lse = __logf(s[0]) + m[0];
    v[n * P2 + j] = EPS * (LOG_NU - lse) + v[n * P2 + j];
}

// ---------------------------------------------------------------------------
// final_pass: pi = exp((u_i - C + v_j)/eps), cost_n = sum(pi*C). One block/row.
// ---------------------------------------------------------------------------
__global__ __launch_bounds__(256) void final_pass(const float* __restrict__ C,
                                                  const float* __restrict__ u,
                                                  const float* __restrict__ v,
                                                  float* __restrict__ pi,
                                                  float* __restrict__ cost) {
    int n = blockIdx.x >> 11, i = blockIdx.x & 2047;
    float ui = u[n * P1 + i];
    const float* Crow = C + ((size_t)(n * P1 + i)) * P2;
    float* Prow = pi + ((size_t)(n * P1 + i)) * P2;
    const float* vb = v + n * P2;
    int t = threadIdx.x;
    float acc = 0.0f;
    for (int k = t; k < P2 / 4; k += 256) {
        float4 c4 = ((const float4*)Crow)[k];
        float4 v4 = ((const float4*)vb)[k];
        float4 p4;
        p4.x = __expf(((ui - c4.x) + v4.x) * INV_EPS);
        p4.y = __expf(((ui - c4.y) + v4.y) * INV_EPS);
        p4.z = __expf(((ui - c4.z) + v4.z) * INV_EPS);
        p4.w = __expf(((ui - c4.w) + v4.w) * INV_EPS);
        ((float4*)Prow)[k] = p4;
        acc += p4.x * c4.x + p4.y * c4.y + p4.z * c4.z + p4.w * c4.w;
    }
    int wave = t >> 6, lane = t & 63;
    #pragma unroll
    for (int o = 1; o < 64; o <<= 1) acc += __shfl_xor(acc, o, 64);
    __shared__ float red[4];
    if (lane == 0) red[wave] = acc;
    __syncthreads();
    if (t == 0) atomicAdd(&cost[n], red[0] + red[1] + red[2] + red[3]);
}

// ---------------------------------------------------------------------------
extern "C" void kernel_launch(void* const* d_in, const int* in_sizes, int n_in,
                              void* d_out, int out_size, void* d_ws, size_t ws_size,
                              hipStream_t stream) {
    const float* x = (const float*)d_in[0];   // [N,P1,D]
    const float* y = (const float*)d_in[1];   // [N,P2,D]
    const float* M = (const float*)d_in[2];   // [D,D]
    float* out = (float*)d_out;
    float* cost = out;                                    // [N]
    float* pi = out + NB;                                 // [N,P1,P2]
    float* C = out + NB + (size_t)NB * P1 * P2;           // [N,P1,P2]

    // pm/ps partials live in the pi output region during iterations
    // (16.8 MB of 67 MB; final_pass overwrites pi afterwards).
    float* pm = pi;                                       // NB*NCHUNK*P2
    float* ps = pi + (size_t)NB * NCHUNK * P2;            // NB*NCHUNK*P2

    float* ws = (float*)d_ws;
    float* S      = ws;                                   // 4096
    float* xS     = S + DD * DD;                          // N*P1*D
    float* dx     = xS + (size_t)NB * P1 * DD;            // N*P1
    float* dy     = dx + NB * P1;                         // N*P2
    float* u      = dy + NB * P2;                         // N*P1
    float* v      = u + NB * P1;                          // N*P2
    float* errAcc = v + NB * P2;                          // 64
    int*   active = (int*)(errAcc + 64);                  // 64 ints

    prep0<<<1, 256, 0, stream>>>(M, S, errAcc, active, cost);
    prep1<<<(NB * (P1 + P2)) / 4, 256, 0, stream>>>(x, y, S, xS, dx, dy, u, v);
    gemmC<<<dim3(P2 / 64, P1 / 64, NB), 256, 0, stream>>>(xS, y, dx, dy, C);
    for (int t = 0; t < ITER; ++t) {
        fused_iter<<<NB * NCHUNK, 512, 0, stream>>>(C, u, v, pm, ps, errAcc, active, t);
        v_comb<<<NB * P2 / 64, 64, 0, stream>>>(pm, ps, v, errAcc, active, t);
    }
    final_pass<<<NB * P1, 256, 0, stream>>>(C, u, v, pi, cost);
}

// Round 3
// 1887.959 us; speedup vs baseline: 3.5174x; 1.3548x over previous
//
#include <hip/hip_runtime.h>
#include <cstdint>
#include <cstddef>

// Problem constants (reference: N=4, P1=P2=2048, D=64, eps=0.1, 50 iters)
#define NB 4
#define P1 2048
#define P2 2048
#define DD 64
#define ITER 50
#define EPS 0.1f
#define INV_EPS 10.0f          // 1.0f/0.1f rounds to exactly 10.0f
#define THRESH 0.1f
// log(1/2048 + 1e-8) in fp32
#define LOG_MU -7.6245985f
#define LOG_NU -7.6245985f
#define ERRSLOTS 32

// ---------------------------------------------------------------------------
// prep0: S = M + M^T, zero err accumulators, init active flags, zero cost out
// ---------------------------------------------------------------------------
__global__ void prep0(const float* __restrict__ M, float* __restrict__ S,
                      float* __restrict__ errAcc, int* __restrict__ active,
                      float* __restrict__ cost) {
    int t = threadIdx.x;
    for (int k = t; k < DD * DD; k += 256) {
        int d = k >> 6, e = k & 63;
        S[k] = M[d * DD + e] + M[e * DD + d];
    }
    for (int k = t; k < ITER * ERRSLOTS; k += 256) errAcc[k] = 0.0f;
    if (t < 64) active[t] = (t == 0) ? 1 : 0;
    if (t < NB) cost[t] = 0.0f;
}

// ---------------------------------------------------------------------------
// prep1: one wave per row. x-rows: xS = x@S, dx = 0.5*x·(Sx), u=0.
//        y-rows: dy = 0.5*y·(Sy), v=0.
// ---------------------------------------------------------------------------
__global__ __launch_bounds__(256) void prep1(const float* __restrict__ x,
                                             const float* __restrict__ y,
                                             const float* __restrict__ S,
                                             float* __restrict__ xS,
                                             float* __restrict__ dx,
                                             float* __restrict__ dy,
                                             float* __restrict__ u,
                                             float* __restrict__ v) {
    __shared__ float Sl[DD * DD];
    int t = threadIdx.x;
    for (int k = t; k < DD * DD; k += 256) Sl[k] = S[k];
    __syncthreads();
    int wave = t >> 6, lane = t & 63;
    int r = blockIdx.x * 4 + wave;          // 0 .. N*(P1+P2)-1
    bool isX = r < NB * P1;
    const float* src = isX ? x : y;
    int rr = isX ? r : r - NB * P1;
    float xv = src[(size_t)rr * DD + lane];
    float acc = 0.0f;
    #pragma unroll
    for (int d = 0; d < DD; ++d) {
        float xd = __shfl(xv, d, 64);
        acc = fmaf(xd, Sl[d * DD + lane], acc);
    }
    float p = acc * xv;
    #pragma unroll
    for (int o = 32; o; o >>= 1) p += __shfl_xor(p, o, 64);
    if (isX) {
        xS[(size_t)rr * DD + lane] = acc;
        if (lane == 0) { dx[rr] = 0.5f * p; u[rr] = 0.0f; }
    } else {
        if (lane == 0) { dy[rr] = 0.5f * p; v[rr] = 0.0f; }
    }
}

// ---------------------------------------------------------------------------
// gemmC: C[n,i,j] = dx[n,i] + dy[n,j] - sum_e xS[n,i,e]*y[n,j,e]
// Also writes Ct[n,j,i] (LDS transpose). 64x64 tile per 256-thread block.
// ---------------------------------------------------------------------------
__global__ __launch_bounds__(256) void gemmC(const float* __restrict__ xS,
                                             const float* __restrict__ y,
                                             const float* __restrict__ dx,
                                             const float* __restrict__ dy,
                                             float* __restrict__ C,
                                             float* __restrict__ Ct) {
    __shared__ float xs[64][68];   // staging; later reused as transpose buffer
    __shared__ float ys[64][68];
    int n = blockIdx.z;
    int i0 = blockIdx.y * 64, j0 = blockIdx.x * 64;
    int t = threadIdx.x;

    #pragma unroll
    for (int k = 0; k < 4; ++k) {
        int f = t + 256 * k;       // 0..1023
        int row = f >> 4;          // 0..63
        int c4 = f & 15;           // 0..15
        float4 a = ((const float4*)xS)[((size_t)(n * P1 + i0 + row)) * (DD / 4) + c4];
        xs[4 * c4 + 0][row] = a.x; xs[4 * c4 + 1][row] = a.y;
        xs[4 * c4 + 2][row] = a.z; xs[4 * c4 + 3][row] = a.w;
        float4 b = ((const float4*)y)[((size_t)(n * P2 + j0 + row)) * (DD / 4) + c4];
        ys[4 * c4 + 0][row] = b.x; ys[4 * c4 + 1][row] = b.y;
        ys[4 * c4 + 2][row] = b.z; ys[4 * c4 + 3][row] = b.w;
    }
    __syncthreads();

    int tx = t & 15, ty = t >> 4;
    float acc[4][4] = {};
    #pragma unroll
    for (int e = 0; e < 64; ++e) {
        float4 a = *(const float4*)&xs[e][4 * ty];
        float4 b = *(const float4*)&ys[e][4 * tx];
        acc[0][0] = fmaf(a.x, b.x, acc[0][0]); acc[0][1] = fmaf(a.x, b.y, acc[0][1]);
        acc[0][2] = fmaf(a.x, b.z, acc[0][2]); acc[0][3] = fmaf(a.x, b.w, acc[0][3]);
        acc[1][0] = fmaf(a.y, b.x, acc[1][0]); acc[1][1] = fmaf(a.y, b.y, acc[1][1]);
        acc[1][2] = fmaf(a.y, b.z, acc[1][2]); acc[1][3] = fmaf(a.y, b.w, acc[1][3]);
        acc[2][0] = fmaf(a.z, b.x, acc[2][0]); acc[2][1] = fmaf(a.z, b.y, acc[2][1]);
        acc[2][2] = fmaf(a.z, b.z, acc[2][2]); acc[2][3] = fmaf(a.z, b.w, acc[2][3]);
        acc[3][0] = fmaf(a.w, b.x, acc[3][0]); acc[3][1] = fmaf(a.w, b.y, acc[3][1]);
        acc[3][2] = fmaf(a.w, b.z, acc[3][2]); acc[3][3] = fmaf(a.w, b.w, acc[3][3]);
    }

    int iBase = i0 + ty * 4, jBase = j0 + tx * 4;
    float4 dy4 = *(const float4*)&dy[n * P2 + jBase];
    #pragma unroll
    for (int r = 0; r < 4; ++r) {
        float dxv = dx[n * P1 + iBase + r];
        acc[r][0] = dxv + dy4.x - acc[r][0];
        acc[r][1] = dxv + dy4.y - acc[r][1];
        acc[r][2] = dxv + dy4.z - acc[r][2];
        acc[r][3] = dxv + dy4.w - acc[r][3];
        *(float4*)&C[((size_t)(n * P1 + iBase + r)) * P2 + jBase] = *(float4*)&acc[r][0];
    }

    // transpose through LDS (reuse xs; pitch 68 floats keeps rows 16B-aligned)
    __syncthreads();
    float* trans = &xs[0][0];
    #pragma unroll
    for (int r = 0; r < 4; ++r)
        #pragma unroll
        for (int c = 0; c < 4; ++c)
            trans[(4 * tx + c) * 68 + 4 * ty + r] = acc[r][c];
    __syncthreads();
    int jl = t >> 2, q = t & 3;
    #pragma unroll
    for (int k = 0; k < 4; ++k) {
        float4 val = *(const float4*)&trans[jl * 68 + q * 16 + 4 * k];
        *(float4*)&Ct[((size_t)(n * P2 + j0 + jl)) * P1 + i0 + q * 16 + 4 * k] = val;
    }
}

// ---------------------------------------------------------------------------
// lse_pass: a_i += eps*(log_w - LSE_j((a_i - Cm_ij + b_j)/eps))
// mode 0 (u-pass over C): accumulate sum|da| into errAcc[t*32 + slot].
// mode 1 (v-pass over Ct): block 0 thread 0 first sets active[t+1] from
//   errAcc[t] (u-pass of iter t is complete).
// 4 rows per 256-thread block, one wave per row, 8 float4 loads in flight.
// ---------------------------------------------------------------------------
__global__ __launch_bounds__(256) void lse_pass(const float* __restrict__ Cm,
                                                float* __restrict__ a,
                                                const float* __restrict__ b,
                                                float* __restrict__ errAcc,
                                                int* __restrict__ active,
                                                int t_iter, int mode) {
    if (mode == 1 && blockIdx.x == 0 && threadIdx.x == 0) {
        float e = 0.0f;
        #pragma unroll
        for (int q = 0; q < ERRSLOTS; ++q) e += errAcc[t_iter * ERRSLOTS + q];
        if (active[t_iter] && (e * 0.25f >= THRESH)) active[t_iter + 1] = 1;
    }
    if (!active[t_iter]) return;
    __shared__ float bl[P2];
    __shared__ float da_s[4];
    int t = threadIdx.x;
    int n = blockIdx.x >> 9;                // 512 blocks per batch
    int i0 = (blockIdx.x & 511) * 4;
    const float* bsrc = b + n * P2;
    for (int k = t; k < P2 / 4; k += 256) ((float4*)bl)[k] = ((const float4*)bsrc)[k];
    __syncthreads();

    int wave = t >> 6, lane = t & 63;
    int i = i0 + wave;
    float ai = a[n * P1 + i];
    const float4* row4 = (const float4*)(Cm + ((size_t)(n * P1 + i)) * P2);

    float4 c[8];
    #pragma unroll
    for (int k = 0; k < 8; ++k) c[k] = row4[lane + 64 * k];

    float m = -3.4e38f;
    #pragma unroll
    for (int k = 0; k < 8; ++k) {
        float4 vv = ((const float4*)bl)[lane + 64 * k];
        c[k].x = ((ai - c[k].x) + vv.x) * INV_EPS;
        c[k].y = ((ai - c[k].y) + vv.y) * INV_EPS;
        c[k].z = ((ai - c[k].z) + vv.z) * INV_EPS;
        c[k].w = ((ai - c[k].w) + vv.w) * INV_EPS;
        m = fmaxf(m, fmaxf(fmaxf(c[k].x, c[k].y), fmaxf(c[k].z, c[k].w)));
    }
    #pragma unroll
    for (int o = 1; o < 64; o <<= 1) m = fmaxf(m, __shfl_xor(m, o, 64));
    float s = 0.0f;
    #pragma unroll
    for (int k = 0; k < 8; ++k)
        s += __expf(c[k].x - m) + __expf(c[k].y - m) +
             __expf(c[k].z - m) + __expf(c[k].w - m);
    #pragma unroll
    for (int o = 1; o < 64; o <<= 1) s += __shfl_xor(s, o, 64);

    if (lane == 0) {
        float lse = __logf(s) + m;
        float anew = EPS * (LOG_MU - lse) + ai;
        a[n * P1 + i] = anew;
        if (mode == 0) da_s[wave] = fabsf(anew - ai);
    }
    if (mode == 0) {
        __syncthreads();
        if (t == 0) {
            float e = da_s[0] + da_s[1] + da_s[2] + da_s[3];
            atomicAdd(&errAcc[t_iter * ERRSLOTS + (blockIdx.x & (ERRSLOTS - 1))], e);
        }
    }
}

// ---------------------------------------------------------------------------
// final_pass: pi = exp((u_i - C + v_j)/eps), cost_n = sum(pi*C).
// 4 rows per 256-thread block, one wave per row, 8 float4 loads in flight.
// ---------------------------------------------------------------------------
__global__ __launch_bounds__(256) void final_pass(const float* __restrict__ C,
                                                  const float* __restrict__ u,
                                                  const float* __restrict__ v,
                                                  float* __restrict__ pi,
                                                  float* __restrict__ cost) {
    __shared__ float vl[P2];
    __shared__ float red[4];
    int t = threadIdx.x;
    int n = blockIdx.x >> 9;
    int i0 = (blockIdx.x & 511) * 4;
    const float* vsrc = v + n * P2;
    for (int k = t; k < P2 / 4; k += 256) ((float4*)vl)[k] = ((const float4*)vsrc)[k];
    __syncthreads();

    int wave = t >> 6, lane = t & 63;
    int i = i0 + wave;
    float ui = u[n * P1 + i];
    const float4* Crow4 = (const float4*)(C + ((size_t)(n * P1 + i)) * P2);
    float4* Prow4 = (float4*)(pi + ((size_t)(n * P1 + i)) * P2);

    float4 c[8];
    #pragma unroll
    for (int k = 0; k < 8; ++k) c[k] = Crow4[lane + 64 * k];

    float acc = 0.0f;
    #pragma unroll
    for (int k = 0; k < 8; ++k) {
        float4 vv = ((const float4*)vl)[lane + 64 * k];
        float4 p4;
        p4.x = __expf(((ui - c[k].x) + vv.x) * INV_EPS);
        p4.y = __expf(((ui - c[k].y) + vv.y) * INV_EPS);
        p4.z = __expf(((ui - c[k].z) + vv.z) * INV_EPS);
        p4.w = __expf(((ui - c[k].w) + vv.w) * INV_EPS);
        Prow4[lane + 64 * k] = p4;
        acc += p4.x * c[k].x + p4.y * c[k].y + p4.z * c[k].z + p4.w * c[k].w;
    }
    #pragma unroll
    for (int o = 1; o < 64; o <<= 1) acc += __shfl_xor(acc, o, 64);
    if (lane == 0) red[wave] = acc;
    __syncthreads();
    if (t == 0) atomicAdd(&cost[n], red[0] + red[1] + red[2] + red[3]);
}

// ---------------------------------------------------------------------------
extern "C" void kernel_launch(void* const* d_in, const int* in_sizes, int n_in,
                              void* d_out, int out_size, void* d_ws, size_t ws_size,
                              hipStream_t stream) {
    const float* x = (const float*)d_in[0];   // [N,P1,D]
    const float* y = (const float*)d_in[1];   // [N,P2,D]
    const float* M = (const float*)d_in[2];   // [D,D]
    float* out = (float*)d_out;
    float* cost = out;                                    // [N]
    float* pi = out + NB;                                 // [N,P1,P2]
    float* C = out + NB + (size_t)NB * P1 * P2;           // [N,P1,P2]

    // Ct (transposed cost) lives in the pi output region during iterations
    // (exactly pi-sized; final_pass overwrites pi afterwards).
    float* Ct = pi;                                       // [N,P2,P1]

    float* ws = (float*)d_ws;
    float* S      = ws;                                   // 4096
    float* xS     = S + DD * DD;                          // N*P1*D
    float* dx     = xS + (size_t)NB * P1 * DD;            // N*P1
    float* dy     = dx + NB * P1;                         // N*P2
    float* u      = dy + NB * P2;                         // N*P1
    float* v      = u + NB * P1;                          // N*P2
    float* errAcc = v + NB * P2;                          // ITER*ERRSLOTS
    int*   active = (int*)(errAcc + ITER * ERRSLOTS);     // 64 ints

    prep0<<<1, 256, 0, stream>>>(M, S, errAcc, active, cost);
    prep1<<<(NB * (P1 + P2)) / 4, 256, 0, stream>>>(x, y, S, xS, dx, dy, u, v);
    gemmC<<<dim3(P2 / 64, P1 / 64, NB), 256, 0, stream>>>(xS, y, dx, dy, C, Ct);
    for (int t = 0; t < ITER; ++t) {
        lse_pass<<<NB * P1 / 4, 256, 0, stream>>>(C,  u, v, errAcc, active, t, 0);
        lse_pass<<<NB * P2 / 4, 256, 0, stream>>>(Ct, v, u, errAcc, active, t, 1);
    }
    final_pass<<<NB * P1 / 4, 256, 0, stream>>>(C, u, v, pi, cost);
}

// Round 4
// 1657.929 us; speedup vs baseline: 4.0054x; 1.1387x over previous
//
#include <hip/hip_runtime.h>
#include <cstdint>
#include <cstddef>

// Problem constants (reference: N=4, P1=P2=2048, D=64, eps=0.1, 50 iters)
#define NB 4
#define P1 2048
#define P2 2048
#define DD 64
#define ITER 50
#define EPS 0.1f
#define INV_EPS 10.0f          // 1.0f/0.1f rounds to exactly 10.0f
#define THRESH 0.1f
// log(1/2048 + 1e-8) in fp32
#define LOG_MU -7.6245985f
#define ELOG (-0.76245985f)    // EPS * LOG_MU
#define ERRSLOTS 32
#define RP (P2 / 4)            // float4s per row

// ---------------------------------------------------------------------------
// prep0: S = M + M^T, zero err accumulators, init active flags, zero cost out
// ---------------------------------------------------------------------------
__global__ void prep0(const float* __restrict__ M, float* __restrict__ S,
                      float* __restrict__ errAcc, int* __restrict__ active,
                      float* __restrict__ cost) {
    int t = threadIdx.x;
    for (int k = t; k < DD * DD; k += 256) {
        int d = k >> 6, e = k & 63;
        S[k] = M[d * DD + e] + M[e * DD + d];
    }
    for (int k = t; k < ITER * ERRSLOTS; k += 256) errAcc[k] = 0.0f;
    if (t < 64) active[t] = (t == 0) ? 1 : 0;
    if (t < NB) cost[t] = 0.0f;
}

// ---------------------------------------------------------------------------
// prep1: one wave per row. x-rows: xS = x@S, dx = 0.5*x·(Sx), u=0.
//        y-rows: dy = 0.5*y·(Sy), v=0.
// ---------------------------------------------------------------------------
__global__ __launch_bounds__(256) void prep1(const float* __restrict__ x,
                                             const float* __restrict__ y,
                                             const float* __restrict__ S,
                                             float* __restrict__ xS,
                                             float* __restrict__ dx,
                                             float* __restrict__ dy,
                                             float* __restrict__ u,
                                             float* __restrict__ v) {
    __shared__ float Sl[DD * DD];
    int t = threadIdx.x;
    for (int k = t; k < DD * DD; k += 256) Sl[k] = S[k];
    __syncthreads();
    int wave = t >> 6, lane = t & 63;
    int r = blockIdx.x * 4 + wave;          // 0 .. N*(P1+P2)-1
    bool isX = r < NB * P1;
    const float* src = isX ? x : y;
    int rr = isX ? r : r - NB * P1;
    float xv = src[(size_t)rr * DD + lane];
    float acc = 0.0f;
    #pragma unroll
    for (int d = 0; d < DD; ++d) {
        float xd = __shfl(xv, d, 64);
        acc = fmaf(xd, Sl[d * DD + lane], acc);
    }
    float p = acc * xv;
    #pragma unroll
    for (int o = 32; o; o >>= 1) p += __shfl_xor(p, o, 64);
    if (isX) {
        xS[(size_t)rr * DD + lane] = acc;
        if (lane == 0) { dx[rr] = 0.5f * p; u[rr] = 0.0f; }
    } else {
        if (lane == 0) { dy[rr] = 0.5f * p; v[rr] = 0.0f; }
    }
}

// ---------------------------------------------------------------------------
// gemmC: C[n,i,j] = dx[n,i] + dy[n,j] - sum_e xS[n,i,e]*y[n,j,e]
// Also writes Ct[n,j,i] (LDS transpose). 64x64 tile per 256-thread block.
// ---------------------------------------------------------------------------
__global__ __launch_bounds__(256) void gemmC(const float* __restrict__ xS,
                                             const float* __restrict__ y,
                                             const float* __restrict__ dx,
                                             const float* __restrict__ dy,
                                             float* __restrict__ C,
                                             float* __restrict__ Ct) {
    __shared__ float xs[64][68];   // staging; later reused as transpose buffer
    __shared__ float ys[64][68];
    int n = blockIdx.z;
    int i0 = blockIdx.y * 64, j0 = blockIdx.x * 64;
    int t = threadIdx.x;

    #pragma unroll
    for (int k = 0; k < 4; ++k) {
        int f = t + 256 * k;       // 0..1023
        int row = f >> 4;          // 0..63
        int c4 = f & 15;           // 0..15
        float4 a = ((const float4*)xS)[((size_t)(n * P1 + i0 + row)) * (DD / 4) + c4];
        xs[4 * c4 + 0][row] = a.x; xs[4 * c4 + 1][row] = a.y;
        xs[4 * c4 + 2][row] = a.z; xs[4 * c4 + 3][row] = a.w;
        float4 b = ((const float4*)y)[((size_t)(n * P2 + j0 + row)) * (DD / 4) + c4];
        ys[4 * c4 + 0][row] = b.x; ys[4 * c4 + 1][row] = b.y;
        ys[4 * c4 + 2][row] = b.z; ys[4 * c4 + 3][row] = b.w;
    }
    __syncthreads();

    int tx = t & 15, ty = t >> 4;
    float acc[4][4] = {};
    #pragma unroll
    for (int e = 0; e < 64; ++e) {
        float4 a = *(const float4*)&xs[e][4 * ty];
        float4 b = *(const float4*)&ys[e][4 * tx];
        acc[0][0] = fmaf(a.x, b.x, acc[0][0]); acc[0][1] = fmaf(a.x, b.y, acc[0][1]);
        acc[0][2] = fmaf(a.x, b.z, acc[0][2]); acc[0][3] = fmaf(a.x, b.w, acc[0][3]);
        acc[1][0] = fmaf(a.y, b.x, acc[1][0]); acc[1][1] = fmaf(a.y, b.y, acc[1][1]);
        acc[1][2] = fmaf(a.y, b.z, acc[1][2]); acc[1][3] = fmaf(a.y, b.w, acc[1][3]);
        acc[2][0] = fmaf(a.z, b.x, acc[2][0]); acc[2][1] = fmaf(a.z, b.y, acc[2][1]);
        acc[2][2] = fmaf(a.z, b.z, acc[2][2]); acc[2][3] = fmaf(a.z, b.w, acc[2][3]);
        acc[3][0] = fmaf(a.w, b.x, acc[3][0]); acc[3][1] = fmaf(a.w, b.y, acc[3][1]);
        acc[3][2] = fmaf(a.w, b.z, acc[3][2]); acc[3][3] = fmaf(a.w, b.w, acc[3][3]);
    }

    int iBase = i0 + ty * 4, jBase = j0 + tx * 4;
    float4 dy4 = *(const float4*)&dy[n * P2 + jBase];
    #pragma unroll
    for (int r = 0; r < 4; ++r) {
        float dxv = dx[n * P1 + iBase + r];
        acc[r][0] = dxv + dy4.x - acc[r][0];
        acc[r][1] = dxv + dy4.y - acc[r][1];
        acc[r][2] = dxv + dy4.z - acc[r][2];
        acc[r][3] = dxv + dy4.w - acc[r][3];
        *(float4*)&C[((size_t)(n * P1 + iBase + r)) * P2 + jBase] = *(float4*)&acc[r][0];
    }

    // transpose through LDS (reuse xs; pitch 68 floats keeps rows 16B-aligned)
    __syncthreads();
    float* trans = &xs[0][0];
    #pragma unroll
    for (int r = 0; r < 4; ++r)
        #pragma unroll
        for (int c = 0; c < 4; ++c)
            trans[(4 * tx + c) * 68 + 4 * ty + r] = acc[r][c];
    __syncthreads();
    int jl = t >> 2, q = t & 3;
    #pragma unroll
    for (int k = 0; k < 4; ++k) {
        float4 val = *(const float4*)&trans[jl * 68 + q * 16 + 4 * k];
        *(float4*)&Ct[((size_t)(n * P2 + j0 + jl)) * P1 + i0 + q * 16 + 4 * k] = val;
    }
}

// ---------------------------------------------------------------------------
// Pipelined row helpers
// ---------------------------------------------------------------------------
__device__ __forceinline__ void load_row8(float4 dst[8], const float4* base, int lane) {
    #pragma unroll
    for (int k = 0; k < 8; ++k) dst[k] = base[lane + 64 * k];
}

// Transforms c in place to q = (ai - C) + b; returns eps*LSE_j(q_j/eps) for
// the wave's row. (max over q commutes with the positive 1/eps scaling.)
__device__ __forceinline__ float row_lse(float4 c[8], float ai, const float* bl, int lane) {
    float m = -3.4e38f;
    #pragma unroll
    for (int k = 0; k < 8; ++k) {
        float4 vv = ((const float4*)bl)[lane + 64 * k];
        c[k].x = (ai - c[k].x) + vv.x;
        c[k].y = (ai - c[k].y) + vv.y;
        c[k].z = (ai - c[k].z) + vv.z;
        c[k].w = (ai - c[k].w) + vv.w;
        m = fmaxf(m, fmaxf(fmaxf(c[k].x, c[k].y), fmaxf(c[k].z, c[k].w)));
    }
    #pragma unroll
    for (int o = 1; o < 64; o <<= 1) m = fmaxf(m, __shfl_xor(m, o, 64));
    float s = 0.0f;
    #pragma unroll
    for (int k = 0; k < 8; ++k)
        s += __expf((c[k].x - m) * INV_EPS) + __expf((c[k].y - m) * INV_EPS) +
             __expf((c[k].z - m) * INV_EPS) + __expf((c[k].w - m) * INV_EPS);
    #pragma unroll
    for (int o = 1; o < 64; o <<= 1) s += __shfl_xor(s, o, 64);
    return EPS * __logf(s) + m;
}

// pi row: writes exp((ui - C + v)/eps), returns partial sum(pi*C) for the lane.
__device__ __forceinline__ float row_pi(const float4 c[8], float ui, const float* vl,
                                        int lane, float4* prow) {
    float acc = 0.0f;
    #pragma unroll
    for (int k = 0; k < 8; ++k) {
        float4 vv = ((const float4*)vl)[lane + 64 * k];
        float4 p;
        p.x = __expf(((ui - c[k].x) + vv.x) * INV_EPS);
        p.y = __expf(((ui - c[k].y) + vv.y) * INV_EPS);
        p.z = __expf(((ui - c[k].z) + vv.z) * INV_EPS);
        p.w = __expf(((ui - c[k].w) + vv.w) * INV_EPS);
        prow[lane + 64 * k] = p;
        acc += p.x * c[k].x + p.y * c[k].y + p.z * c[k].z + p.w * c[k].w;
    }
    return acc;
}

// ---------------------------------------------------------------------------
// lse_pass: a_i += eps*(log_w - LSE_j((a_i - Cm_ij + b_j)/eps))
// 16 rows per 256-thread block (4 rows/wave, ping-pong prefetch: load row r+1
// while computing row r). Grid = NB * P1/16 = 512 blocks = 2/CU exactly.
// mode 0 (u over C): accumulate sum|da|. mode 1 (v over Ct): update active.
// ---------------------------------------------------------------------------
__global__ __launch_bounds__(256) void lse_pass(const float* __restrict__ Cm,
                                                float* __restrict__ a,
                                                const float* __restrict__ b,
                                                float* __restrict__ errAcc,
                                                int* __restrict__ active,
                                                int t_iter, int mode) {
    if (mode == 1 && blockIdx.x == 0 && threadIdx.x == 0) {
        float e = 0.0f;
        #pragma unroll
        for (int q = 0; q < ERRSLOTS; ++q) e += errAcc[t_iter * ERRSLOTS + q];
        if (active[t_iter] && (e * 0.25f >= THRESH)) active[t_iter + 1] = 1;
    }
    if (!active[t_iter]) return;
    __shared__ float bl[P2];
    __shared__ float da_s[4];
    int t = threadIdx.x;
    int n = blockIdx.x >> 7;                 // 128 blocks per batch
    int i0 = (blockIdx.x & 127) * 16;
    {
        const float4* bsrc = (const float4*)(b + n * P2);
        ((float4*)bl)[t] = bsrc[t];
        ((float4*)bl)[t + 256] = bsrc[t + 256];
    }
    __syncthreads();

    int wave = t >> 6, lane = t & 63;
    int irow = i0 + wave * 4;
    float* arow = a + n * P1 + irow;
    float a0 = arow[0], a1 = arow[1], a2 = arow[2], a3 = arow[3];
    const float4* base = (const float4*)(Cm + ((size_t)(n * P1 + irow)) * P2);

    float4 A[8], B[8];
    load_row8(A, base, lane);
    load_row8(B, base + RP, lane);
    float l0 = row_lse(A, a0, bl, lane);
    load_row8(A, base + 2 * RP, lane);
    float l1 = row_lse(B, a1, bl, lane);
    load_row8(B, base + 3 * RP, lane);
    float l2 = row_lse(A, a2, bl, lane);
    float l3 = row_lse(B, a3, bl, lane);

    float n0 = a0 + ELOG - l0;
    float n1 = a1 + ELOG - l1;
    float n2 = a2 + ELOG - l2;
    float n3 = a3 + ELOG - l3;
    if (lane == 0) {
        arow[0] = n0; arow[1] = n1; arow[2] = n2; arow[3] = n3;
        if (mode == 0)
            da_s[wave] = fabsf(n0 - a0) + fabsf(n1 - a1) +
                         fabsf(n2 - a2) + fabsf(n3 - a3);
    }
    if (mode == 0) {
        __syncthreads();
        if (t == 0) {
            float e = da_s[0] + da_s[1] + da_s[2] + da_s[3];
            atomicAdd(&errAcc[t_iter * ERRSLOTS + (blockIdx.x & (ERRSLOTS - 1))], e);
        }
    }
}

// ---------------------------------------------------------------------------
// final_pass: pi = exp((u_i - C + v_j)/eps), cost_n = sum(pi*C).
// Same pipelined 16-rows/block structure.
// ---------------------------------------------------------------------------
__global__ __launch_bounds__(256) void final_pass(const float* __restrict__ C,
                                                  const float* __restrict__ u,
                                                  const float* __restrict__ v,
                                                  float* __restrict__ pi,
                                                  float* __restrict__ cost) {
    __shared__ float vl[P2];
    __shared__ float red[4];
    int t = threadIdx.x;
    int n = blockIdx.x >> 7;
    int i0 = (blockIdx.x & 127) * 16;
    {
        const float4* vsrc = (const float4*)(v + n * P2);
        ((float4*)vl)[t] = vsrc[t];
        ((float4*)vl)[t + 256] = vsrc[t + 256];
    }
    __syncthreads();

    int wave = t >> 6, lane = t & 63;
    int irow = i0 + wave * 4;
    const float* urow = u + n * P1 + irow;
    float u0 = urow[0], u1 = urow[1], u2 = urow[2], u3 = urow[3];
    const float4* base = (const float4*)(C + ((size_t)(n * P1 + irow)) * P2);
    float4* pbase = (float4*)(pi + ((size_t)(n * P1 + irow)) * P2);

    float4 A[8], B[8];
    load_row8(A, base, lane);
    load_row8(B, base + RP, lane);
    float acc = row_pi(A, u0, vl, lane, pbase);
    load_row8(A, base + 2 * RP, lane);
    acc += row_pi(B, u1, vl, lane, pbase + RP);
    load_row8(B, base + 3 * RP, lane);
    acc += row_pi(A, u2, vl, lane, pbase + 2 * RP);
    acc += row_pi(B, u3, vl, lane, pbase + 3 * RP);

    #pragma unroll
    for (int o = 1; o < 64; o <<= 1) acc += __shfl_xor(acc, o, 64);
    if (lane == 0) red[wave] = acc;
    __syncthreads();
    if (t == 0) atomicAdd(&cost[n], red[0] + red[1] + red[2] + red[3]);
}

// ---------------------------------------------------------------------------
extern "C" void kernel_launch(void* const* d_in, const int* in_sizes, int n_in,
                              void* d_out, int out_size, void* d_ws, size_t ws_size,
                              hipStream_t stream) {
    const float* x = (const float*)d_in[0];   // [N,P1,D]
    const float* y = (const float*)d_in[1];   // [N,P2,D]
    const float* M = (const float*)d_in[2];   // [D,D]
    float* out = (float*)d_out;
    float* cost = out;                                    // [N]
    float* pi = out + NB;                                 // [N,P1,P2]
    float* C = out + NB + (size_t)NB * P1 * P2;           // [N,P1,P2]

    // Ct (transposed cost) lives in the pi output region during iterations
    // (exactly pi-sized; final_pass overwrites pi afterwards).
    float* Ct = pi;                                       // [N,P2,P1]

    float* ws = (float*)d_ws;
    float* S      = ws;                                   // 4096
    float* xS     = S + DD * DD;                          // N*P1*D
    float* dx     = xS + (size_t)NB * P1 * DD;            // N*P1
    float* dy     = dx + NB * P1;                         // N*P2
    float* u      = dy + NB * P2;                         // N*P1
    float* v      = u + NB * P1;                          // N*P2
    float* errAcc = v + NB * P2;                          // ITER*ERRSLOTS
    int*   active = (int*)(errAcc + ITER * ERRSLOTS);     // 64 ints

    prep0<<<1, 256, 0, stream>>>(M, S, errAcc, active, cost);
    prep1<<<(NB * (P1 + P2)) / 4, 256, 0, stream>>>(x, y, S, xS, dx, dy, u, v);
    gemmC<<<dim3(P2 / 64, P1 / 64, NB), 256, 0, stream>>>(xS, y, dx, dy, C, Ct);
    for (int t = 0; t < ITER; ++t) {
        lse_pass<<<NB * P1 / 16, 256, 0, stream>>>(C,  u, v, errAcc, active, t, 0);
        lse_pass<<<NB * P2 / 16, 256, 0, stream>>>(Ct, v, u, errAcc, active, t, 1);
    }
    final_pass<<<NB * P1 / 16, 256, 0, stream>>>(C, u, v, pi, cost);
}

// Round 6
// 1610.340 us; speedup vs baseline: 4.1238x; 1.0296x over previous
//
#include <hip/hip_runtime.h>
#include <cstdint>
#include <cstddef>

// Problem constants (reference: N=4, P1=P2=2048, D=64, eps=0.1, 50 iters)
#define NB 4
#define P1 2048
#define P2 2048
#define DD 64
#define ITER 50
#define EPS 0.1f
#define INV_EPS 10.0f          // 1.0f/0.1f rounds to exactly 10.0f
#define THRESH 0.1f
// log(1/2048 + 1e-8) in fp32
#define LOG_MU -7.6245985f
#define ELOG (-0.76245985f)    // EPS * LOG_MU (== EPS * LOG_NU)
#define ERRSLOTS 32
#define RP (P2 / 4)            // float4s per row
#define PCHUNKS 128            // iter_pass blocks per batch (16 rows each)

// ---------------------------------------------------------------------------
// prep0: S = M + M^T, zero err accumulators, init active flags, zero cost out
// ---------------------------------------------------------------------------
__global__ void prep0(const float* __restrict__ M, float* __restrict__ S,
                      float* __restrict__ errAcc, int* __restrict__ active,
                      float* __restrict__ cost) {
    int t = threadIdx.x;
    for (int k = t; k < DD * DD; k += 256) {
        int d = k >> 6, e = k & 63;
        S[k] = M[d * DD + e] + M[e * DD + d];
    }
    for (int k = t; k < ITER * ERRSLOTS; k += 256) errAcc[k] = 0.0f;
    if (t < 64) active[t] = (t == 0) ? 1 : 0;
    if (t < NB) cost[t] = 0.0f;
}

// ---------------------------------------------------------------------------
// prep1: one wave per row. x-rows: xS = x@S, dx = 0.5*x·(Sx), u=0.
//        y-rows: dy = 0.5*y·(Sy), v=0.
// ---------------------------------------------------------------------------
__global__ __launch_bounds__(256) void prep1(const float* __restrict__ x,
                                             const float* __restrict__ y,
                                             const float* __restrict__ S,
                                             float* __restrict__ xS,
                                             float* __restrict__ dx,
                                             float* __restrict__ dy,
                                             float* __restrict__ u,
                                             float* __restrict__ v) {
    __shared__ float Sl[DD * DD];
    int t = threadIdx.x;
    for (int k = t; k < DD * DD; k += 256) Sl[k] = S[k];
    __syncthreads();
    int wave = t >> 6, lane = t & 63;
    int r = blockIdx.x * 4 + wave;          // 0 .. N*(P1+P2)-1
    bool isX = r < NB * P1;
    const float* src = isX ? x : y;
    int rr = isX ? r : r - NB * P1;
    float xv = src[(size_t)rr * DD + lane];
    float acc = 0.0f;
    #pragma unroll
    for (int d = 0; d < DD; ++d) {
        float xd = __shfl(xv, d, 64);
        acc = fmaf(xd, Sl[d * DD + lane], acc);
    }
    float p = acc * xv;
    #pragma unroll
    for (int o = 32; o; o >>= 1) p += __shfl_xor(p, o, 64);
    if (isX) {
        xS[(size_t)rr * DD + lane] = acc;
        if (lane == 0) { dx[rr] = 0.5f * p; u[rr] = 0.0f; }
    } else {
        if (lane == 0) { dy[rr] = 0.5f * p; v[rr] = 0.0f; }
    }
}

// ---------------------------------------------------------------------------
// gemmC: C[n,i,j] = dx[n,i] + dy[n,j] - sum_e xS[n,i,e]*y[n,j,e]
// 64x64 tile per 256-thread block, 4x4 register tile per thread.
// ---------------------------------------------------------------------------
__global__ __launch_bounds__(256) void gemmC(const float* __restrict__ xS,
                                             const float* __restrict__ y,
                                             const float* __restrict__ dx,
                                             const float* __restrict__ dy,
                                             float* __restrict__ C) {
    __shared__ float xs[64][68];
    __shared__ float ys[64][68];
    int n = blockIdx.z;
    int i0 = blockIdx.y * 64, j0 = blockIdx.x * 64;
    int t = threadIdx.x;

    #pragma unroll
    for (int k = 0; k < 4; ++k) {
        int f = t + 256 * k;       // 0..1023
        int row = f >> 4;          // 0..63
        int c4 = f & 15;           // 0..15
        float4 a = ((const float4*)xS)[((size_t)(n * P1 + i0 + row)) * (DD / 4) + c4];
        xs[4 * c4 + 0][row] = a.x; xs[4 * c4 + 1][row] = a.y;
        xs[4 * c4 + 2][row] = a.z; xs[4 * c4 + 3][row] = a.w;
        float4 b = ((const float4*)y)[((size_t)(n * P2 + j0 + row)) * (DD / 4) + c4];
        ys[4 * c4 + 0][row] = b.x; ys[4 * c4 + 1][row] = b.y;
        ys[4 * c4 + 2][row] = b.z; ys[4 * c4 + 3][row] = b.w;
    }
    __syncthreads();

    int tx = t & 15, ty = t >> 4;
    float acc[4][4] = {};
    #pragma unroll
    for (int e = 0; e < 64; ++e) {
        float4 a = *(const float4*)&xs[e][4 * ty];
        float4 b = *(const float4*)&ys[e][4 * tx];
        acc[0][0] = fmaf(a.x, b.x, acc[0][0]); acc[0][1] = fmaf(a.x, b.y, acc[0][1]);
        acc[0][2] = fmaf(a.x, b.z, acc[0][2]); acc[0][3] = fmaf(a.x, b.w, acc[0][3]);
        acc[1][0] = fmaf(a.y, b.x, acc[1][0]); acc[1][1] = fmaf(a.y, b.y, acc[1][1]);
        acc[1][2] = fmaf(a.y, b.z, acc[1][2]); acc[1][3] = fmaf(a.y, b.w, acc[1][3]);
        acc[2][0] = fmaf(a.z, b.x, acc[2][0]); acc[2][1] = fmaf(a.z, b.y, acc[2][1]);
        acc[2][2] = fmaf(a.z, b.z, acc[2][2]); acc[2][3] = fmaf(a.z, b.w, acc[2][3]);
        acc[3][0] = fmaf(a.w, b.x, acc[3][0]); acc[3][1] = fmaf(a.w, b.y, acc[3][1]);
        acc[3][2] = fmaf(a.w, b.z, acc[3][2]); acc[3][3] = fmaf(a.w, b.w, acc[3][3]);
    }

    int iBase = i0 + ty * 4, jBase = j0 + tx * 4;
    float4 dy4 = *(const float4*)&dy[n * P2 + jBase];
    #pragma unroll
    for (int r = 0; r < 4; ++r) {
        float dxv = dx[n * P1 + iBase + r];
        float4 o;
        o.x = dxv + dy4.x - acc[r][0];
        o.y = dxv + dy4.y - acc[r][1];
        o.z = dxv + dy4.z - acc[r][2];
        o.w = dxv + dy4.w - acc[r][3];
        *(float4*)&C[((size_t)(n * P1 + iBase + r)) * P2 + jBase] = o;
    }
}

// ---------------------------------------------------------------------------
// Row helpers (r4-validated)
// ---------------------------------------------------------------------------
__device__ __forceinline__ void load_row8(float4 dst[8], const float4* base, int lane) {
    #pragma unroll
    for (int k = 0; k < 8; ++k) dst[k] = base[lane + 64 * k];
}

// Transforms c in place to q = (ai - C) + b; returns eps*LSE_j(q_j/eps).
__device__ __forceinline__ float row_lse(float4 c[8], float ai, const float* bl, int lane) {
    float m = -3.4e38f;
    #pragma unroll
    for (int k = 0; k < 8; ++k) {
        float4 vv = ((const float4*)bl)[lane + 64 * k];
        c[k].x = (ai - c[k].x) + vv.x;
        c[k].y = (ai - c[k].y) + vv.y;
        c[k].z = (ai - c[k].z) + vv.z;
        c[k].w = (ai - c[k].w) + vv.w;
        m = fmaxf(m, fmaxf(fmaxf(c[k].x, c[k].y), fmaxf(c[k].z, c[k].w)));
    }
    #pragma unroll
    for (int o = 1; o < 64; o <<= 1) m = fmaxf(m, __shfl_xor(m, o, 64));
    float s = 0.0f;
    #pragma unroll
    for (int k = 0; k < 8; ++k)
        s += __expf((c[k].x - m) * INV_EPS) + __expf((c[k].y - m) * INV_EPS) +
             __expf((c[k].z - m) * INV_EPS) + __expf((c[k].w - m) * INV_EPS);
    #pragma unroll
    for (int o = 1; o < 64; o <<= 1) s += __shfl_xor(s, o, 64);
    return EPS * __logf(s) + m;
}

// Online (m,s) merge of one scalar term q (values in C-units, exp scaled by 1/eps)
__device__ __forceinline__ void mergec(float& m, float& s, float q) {
    float nm = fmaxf(m, q);
    s = s * __expf((m - nm) * INV_EPS) + __expf((q - nm) * INV_EPS);
    m = nm;
}
__device__ __forceinline__ void mergems(float& m, float& s, float mo, float so) {
    float nm = fmaxf(m, mo);
    s = s * __expf((m - nm) * INV_EPS) + so * __expf((mo - nm) * INV_EPS);
    m = nm;
}
__device__ __forceinline__ void merge44(float4& m, float4& s, float4 mo, float4 so) {
    mergems(m.x, s.x, mo.x, so.x);
    mergems(m.y, s.y, mo.y, so.y);
    mergems(m.z, s.z, mo.z, so.z);
    mergems(m.w, s.w, mo.w, so.w);
}

// Merge row's q (+wave-uniform dr = u_new - u_old) into per-column (M,S) regs.
__device__ __forceinline__ void merge_row(float4 M[8], float4 S[8],
                                          const float4 q[8], float dr) {
    #pragma unroll
    for (int k = 0; k < 8; ++k) {
        mergec(M[k].x, S[k].x, q[k].x + dr);
        mergec(M[k].y, S[k].y, q[k].y + dr);
        mergec(M[k].z, S[k].z, q[k].z + dr);
        mergec(M[k].w, S[k].w, q[k].w + dr);
    }
}

// ---------------------------------------------------------------------------
// iter_pass: full Sinkhorn u-update (identical arithmetic to r4's lse_pass)
// PLUS in-register per-column (m,s) partials using the fresh u (q + dr trick:
// exp((u_new - C + v)/eps) = exp((q + (u_new-u_old))/eps), dr wave-uniform).
// C is read ONCE per iteration; no Ct, no re-reads. 16 rows/block, 512 blocks.
// Partials (one (m,s) per column per block) -> pm/ps; v_comb finishes v.
// ---------------------------------------------------------------------------
__global__ __launch_bounds__(256) void iter_pass(const float* __restrict__ C,
                                                 float* __restrict__ u,
                                                 const float* __restrict__ v,
                                                 float* __restrict__ pm,
                                                 float* __restrict__ ps,
                                                 float* __restrict__ errAcc,
                                                 const int* __restrict__ active,
                                                 int t_iter) {
    if (!active[t_iter]) return;
    __shared__ float bl[P2];          // 8 KB: v values for this batch
    __shared__ float4 LM[4][512];     // 32 KB: per-wave column maxima
    __shared__ float4 LS[4][512];     // 32 KB: per-wave column sums
    __shared__ float da_s[4];
    int t = threadIdx.x;
    int n = blockIdx.x >> 7;                       // PCHUNKS=128 blocks/batch
    int i0 = (blockIdx.x & (PCHUNKS - 1)) * 16;
    {
        const float4* bsrc = (const float4*)(v + n * P2);
        ((float4*)bl)[t] = bsrc[t];
        ((float4*)bl)[t + 256] = bsrc[t + 256];
    }
    __syncthreads();

    int wave = t >> 6, lane = t & 63;
    int irow = i0 + wave * 4;
    float* arow = u + n * P1 + irow;
    float a0 = arow[0], a1 = arow[1], a2 = arow[2], a3 = arow[3];
    const float4* base = (const float4*)(C + ((size_t)(n * P1 + irow)) * P2);

    float4 M[8], S[8];
    #pragma unroll
    for (int k = 0; k < 8; ++k) {
        M[k] = make_float4(-3.4e38f, -3.4e38f, -3.4e38f, -3.4e38f);
        S[k] = make_float4(0.0f, 0.0f, 0.0f, 0.0f);
    }

    float4 A[8], B[8];
    load_row8(A, base, lane);
    load_row8(B, base + RP, lane);
    float l0 = row_lse(A, a0, bl, lane);
    float d0 = ELOG - l0;
    merge_row(M, S, A, d0);
    load_row8(A, base + 2 * RP, lane);
    float l1 = row_lse(B, a1, bl, lane);
    float d1 = ELOG - l1;
    merge_row(M, S, B, d1);
    load_row8(B, base + 3 * RP, lane);
    float l2 = row_lse(A, a2, bl, lane);
    float d2 = ELOG - l2;
    merge_row(M, S, A, d2);
    float l3 = row_lse(B, a3, bl, lane);
    float d3 = ELOG - l3;
    merge_row(M, S, B, d3);

    if (lane == 0) {
        arow[0] = a0 + d0; arow[1] = a1 + d1;
        arow[2] = a2 + d2; arow[3] = a3 + d3;
        da_s[wave] = fabsf(d0) + fabsf(d1) + fabsf(d2) + fabsf(d3);
    }

    // cross-wave column merge through LDS
    #pragma unroll
    for (int k = 0; k < 8; ++k) {
        LM[wave][lane + 64 * k] = M[k];
        LS[wave][lane + 64 * k] = S[k];
    }
    __syncthreads();

    float4* pm4 = (float4*)pm;
    float4* ps4 = (float4*)ps;
    size_t pb4 = (size_t)blockIdx.x * 512;
    #pragma unroll
    for (int sl = 0; sl < 2; ++sl) {
        int slot = t + 256 * sl;
        float4 m = LM[0][slot], s = LS[0][slot];
        merge44(m, s, LM[1][slot], LS[1][slot]);
        merge44(m, s, LM[2][slot], LS[2][slot]);
        merge44(m, s, LM[3][slot], LS[3][slot]);
        pm4[pb4 + slot] = m;
        ps4[pb4 + slot] = s;
    }

    if (t == 0) {
        atomicAdd(&errAcc[t_iter * ERRSLOTS + (blockIdx.x & (ERRSLOTS - 1))],
                  da_s[0] + da_s[1] + da_s[2] + da_s[3]);
    }
}

// ---------------------------------------------------------------------------
// v_comb: merge PCHUNKS (m,s) partials per column, apply v update, advance
// active. 128 blocks x 256 threads; block handles 64 columns, wave w merges
// partial-chunks [32w, 32w+32), LDS tree finishes.
// ---------------------------------------------------------------------------
__global__ __launch_bounds__(256) void v_comb(const float* __restrict__ pm,
                                              const float* __restrict__ ps,
                                              float* __restrict__ v,
                                              const float* __restrict__ errAcc,
                                              int* __restrict__ active,
                                              int t_iter) {
    if (blockIdx.x == 0 && threadIdx.x == 0) {
        float e = 0.0f;
        #pragma unroll
        for (int q = 0; q < ERRSLOTS; ++q) e += errAcc[t_iter * ERRSLOTS + q];
        if (active[t_iter] && (e * 0.25f >= THRESH)) active[t_iter + 1] = 1;
    }
    if (!active[t_iter]) return;
    __shared__ float LMv[4][64];
    __shared__ float LSv[4][64];
    int t = threadIdx.x, wave = t >> 6, lane = t & 63;
    int n = blockIdx.x >> 5;
    int j = ((blockIdx.x & 31) << 6) + lane;
    const float* pmb = pm + ((size_t)(n * PCHUNKS + wave * 32)) * P2 + j;
    const float* psb = ps + ((size_t)(n * PCHUNKS + wave * 32)) * P2 + j;
    float m0 = -3.4e38f, s0 = 0.0f, m1 = -3.4e38f, s1 = 0.0f;
    float m2 = -3.4e38f, s2 = 0.0f, m3 = -3.4e38f, s3 = 0.0f;
    #pragma unroll
    for (int c = 0; c < 32; c += 4) {
        mergems(m0, s0, pmb[(size_t)(c + 0) * P2], psb[(size_t)(c + 0) * P2]);
        mergems(m1, s1, pmb[(size_t)(c + 1) * P2], psb[(size_t)(c + 1) * P2]);
        mergems(m2, s2, pmb[(size_t)(c + 2) * P2], psb[(size_t)(c + 2) * P2]);
        mergems(m3, s3, pmb[(size_t)(c + 3) * P2], psb[(size_t)(c + 3) * P2]);
    }
    mergems(m0, s0, m1, s1);
    mergems(m2, s2, m3, s3);
    mergems(m0, s0, m2, s2);
    LMv[wave][lane] = m0; LSv[wave][lane] = s0;
    __syncthreads();
    if (wave == 0) {
        float m = LMv[0][lane], s = LSv[0][lane];
        mergems(m, s, LMv[1][lane], LSv[1][lane]);
        mergems(m, s, LMv[2][lane], LSv[2][lane]);
        mergems(m, s, LMv[3][lane], LSv[3][lane]);
        float lse = EPS * __logf(s) + m;
        v[n * P2 + j] = v[n * P2 + j] + ELOG - lse;
    }
}

// ---------------------------------------------------------------------------
// final_pass: pi = exp((u_i - C + v_j)/eps), cost_n = sum(pi*C).
// Pipelined 16-rows/block structure (r4-validated).
// ---------------------------------------------------------------------------
__device__ __forceinline__ float row_pi(const float4 c[8], float ui, const float* vl,
                                        int lane, float4* prow) {
    float acc = 0.0f;
    #pragma unroll
    for (int k = 0; k < 8; ++k) {
        float4 vv = ((const float4*)vl)[lane + 64 * k];
        float4 p;
        p.x = __expf(((ui - c[k].x) + vv.x) * INV_EPS);
        p.y = __expf(((ui - c[k].y) + vv.y) * INV_EPS);
        p.z = __expf(((ui - c[k].z) + vv.z) * INV_EPS);
        p.w = __expf(((ui - c[k].w) + vv.w) * INV_EPS);
        prow[lane + 64 * k] = p;
        acc += p.x * c[k].x + p.y * c[k].y + p.z * c[k].z + p.w * c[k].w;
    }
    return acc;
}

__global__ __launch_bounds__(256) void final_pass(const float* __restrict__ C,
                                                  const float* __restrict__ u,
                                                  const float* __restrict__ v,
                                                  float* __restrict__ pi,
                                                  float* __restrict__ cost) {
    __shared__ float vl[P2];
    __shared__ float red[4];
    int t = threadIdx.x;
    int n = blockIdx.x >> 7;
    int i0 = (blockIdx.x & 127) * 16;
    {
        const float4* vsrc = (const float4*)(v + n * P2);
        ((float4*)vl)[t] = vsrc[t];
        ((float4*)vl)[t + 256] = vsrc[t + 256];
    }
    __syncthreads();

    int wave = t >> 6, lane = t & 63;
    int irow = i0 + wave * 4;
    const float* urow = u + n * P1 + irow;
    float u0 = urow[0], u1 = urow[1], u2 = urow[2], u3 = urow[3];
    const float4* base = (const float4*)(C + ((size_t)(n * P1 + irow)) * P2);
    float4* pbase = (float4*)(pi + ((size_t)(n * P1 + irow)) * P2);

    float4 A[8], B[8];
    load_row8(A, base, lane);
    load_row8(B, base + RP, lane);
    float acc = row_pi(A, u0, vl, lane, pbase);
    load_row8(A, base + 2 * RP, lane);
    acc += row_pi(B, u1, vl, lane, pbase + RP);
    load_row8(B, base + 3 * RP, lane);
    acc += row_pi(A, u2, vl, lane, pbase + 2 * RP);
    acc += row_pi(B, u3, vl, lane, pbase + 3 * RP);

    #pragma unroll
    for (int o = 1; o < 64; o <<= 1) acc += __shfl_xor(acc, o, 64);
    if (lane == 0) red[wave] = acc;
    __syncthreads();
    if (t == 0) atomicAdd(&cost[n], red[0] + red[1] + red[2] + red[3]);
}

// ---------------------------------------------------------------------------
extern "C" void kernel_launch(void* const* d_in, const int* in_sizes, int n_in,
                              void* d_out, int out_size, void* d_ws, size_t ws_size,
                              hipStream_t stream) {
    const float* x = (const float*)d_in[0];   // [N,P1,D]
    const float* y = (const float*)d_in[1];   // [N,P2,D]
    const float* M = (const float*)d_in[2];   // [D,D]
    float* out = (float*)d_out;
    float* cost = out;                                    // [N]
    float* pi = out + NB;                                 // [N,P1,P2]
    float* C = out + NB + (size_t)NB * P1 * P2;           // [N,P1,P2]

    float* ws = (float*)d_ws;
    float* S      = ws;                                   // 4096
    float* xS     = S + DD * DD;                          // N*P1*D
    float* dx     = xS + (size_t)NB * P1 * DD;            // N*P1
    float* dy     = dx + NB * P1;                         // N*P2
    float* u      = dy + NB * P2;                         // N*P1
    float* v      = u + NB * P1;                          // N*P2
    float* errAcc = v + NB * P2;                          // ITER*ERRSLOTS
    int*   active = (int*)(errAcc + ITER * ERRSLOTS);     // 64 ints
    float* ws_end = (float*)(active + 64);

    // pm/ps: one (m,s) per column per iter_pass block = 2 * NB*PCHUNKS*P2
    // floats = 8.4 MB. Prefer ws; fall back to the pi region (dead until
    // final_pass) if ws is too small. Branch is on a launch-constant.
    size_t base_floats = (size_t)(ws_end - ws);
    size_t pmps_floats = 2 * (size_t)NB * PCHUNKS * P2;
    float* pm;
    float* ps;
    if (ws_size >= (base_floats + pmps_floats) * sizeof(float)) {
        pm = ws_end;
        ps = ws_end + pmps_floats / 2;
    } else {
        pm = pi;
        ps = pi + pmps_floats / 2;
    }

    prep0<<<1, 256, 0, stream>>>(M, S, errAcc, active, cost);
    prep1<<<(NB * (P1 + P2)) / 4, 256, 0, stream>>>(x, y, S, xS, dx, dy, u, v);
    gemmC<<<dim3(P2 / 64, P1 / 64, NB), 256, 0, stream>>>(xS, y, dx, dy, C);
    for (int t = 0; t < ITER; ++t) {
        iter_pass<<<NB * PCHUNKS, 256, 0, stream>>>(C, u, v, pm, ps, errAcc, active, t);
        v_comb<<<NB * 32, 256, 0, stream>>>(pm, ps, v, errAcc, active, t);
    }
    final_pass<<<NB * P1 / 16, 256, 0, stream>>>(C, u, v, pi, cost);
}